// Round 1
// baseline (2857.911 us; speedup 1.0000x reference)
//
#include <hip/hip_runtime.h>

typedef unsigned short u16;
typedef unsigned int   u32;
typedef unsigned long long u64;
typedef __attribute__((ext_vector_type(4))) float f32x4;
typedef __attribute__((ext_vector_type(8))) short s16x8;
typedef __attribute__((ext_vector_type(4))) unsigned short u16x4;
typedef __attribute__((ext_vector_type(8))) unsigned short u16x8;

__device__ __forceinline__ float bf2f(u16 u) {
    u32 i = ((u32)u) << 16;
    return __builtin_bit_cast(float, i);
}
__device__ __forceinline__ u16 f2bf(float f) {  // round-nearest-even, finite inputs
    u32 i = __builtin_bit_cast(u32, f);
    u32 lsb = (i >> 16) & 1u;
    i += 0x7fffu + lsb;
    return (u16)(i >> 16);
}

// ---------------------------------------------------------------------------
// prep: convert W_ih -> bf16 (row-major [1536][512]) and W_hh -> bf16 in MFMA
// B-fragment order: Wfrag[w][gate][kstep][lane][8], w=h-col-tile (32), kstep=K/32.
// 98304 threads, each handles one 8-element chunk of each.
// ---------------------------------------------------------------------------
__global__ __launch_bounds__(256) void prep(const float* __restrict__ Wih,
                                            const float* __restrict__ Whh,
                                            u16* __restrict__ Wihb,
                                            u16* __restrict__ Wfrag) {
    int id = blockIdx.x * 256 + threadIdx.x;  // [0, 98304)
    // (a) W_ih bf16 copy
    {
        const float* s = Wih + (size_t)id * 8;
        f32x4 x0 = *(const f32x4*)s;
        f32x4 x1 = *(const f32x4*)(s + 4);
        u16x8 o;
        for (int j = 0; j < 4; ++j) { o[j] = f2bf(x0[j]); o[4 + j] = f2bf(x1[j]); }
        *(u16x8*)(Wihb + (size_t)id * 8) = o;
    }
    // (b) W_hh fragment-ordered
    {
        int lane = id & 63;
        int ks   = (id >> 6) & 15;
        int wnt  = id >> 10;          // w*3 + nt
        int nt   = wnt % 3;
        int w    = wnt / 3;
        int row  = nt * 512 + w * 16 + (lane & 15);   // gh row
        int k    = ks * 32 + (lane >> 4) * 8;
        const float* s = Whh + (size_t)row * 512 + k;
        f32x4 x0 = *(const f32x4*)s;
        f32x4 x1 = *(const f32x4*)(s + 4);
        u16x8 o;
        for (int j = 0; j < 4; ++j) { o[j] = f2bf(x0[j]); o[4 + j] = f2bf(x1[j]); }
        *(u16x8*)(Wfrag + (size_t)id * 8) = o;
    }
}

// ---------------------------------------------------------------------------
// gemm_xproj: C[m'=s*64+b][n] = input[b][s][:] . W_ih[n][:] + b_ih[n]
// 128x128 tile, BK=64, 4 waves, 4x4 16x16x32 fragments per wave.
// A is fp32 in global (transposed on the fly during reg-staged conversion);
// B (W_ih bf16) staged via global_load_lds width 16.
// Epilogue writes bf16 directly in phase-2 fragment order:
//   el = (((s*32 + w)*4 + mt)*3 + g)*256 + lane*4 + j
// ---------------------------------------------------------------------------
__global__ __launch_bounds__(256) void gemm_xproj(const float* __restrict__ inp,
                                                  const u16* __restrict__ Wihb,
                                                  const float* __restrict__ bih,
                                                  u16* __restrict__ xp) {
    __shared__ u16 lA[128 * 64];
    __shared__ u16 lB[128 * 64];
    const int bid = blockIdx.x;
    const int mtile = bid & 255;   // 256 m-tiles (M = 32768)
    const int ntile = bid >> 8;    // 12 n-tiles  (N = 1536)
    const int tid = threadIdx.x;
    const int l = tid & 63;
    const int wid = tid >> 6;
    const int s0 = mtile * 2;
    const int n0 = ntile * 128;

    f32x4 acc[4][4];
    for (int a = 0; a < 4; ++a)
        for (int b = 0; b < 4; ++b) acc[a][b] = (f32x4){0.f, 0.f, 0.f, 0.f};

    for (int k0 = 0; k0 < 512; k0 += 64) {
        if (k0) __syncthreads();
        // B tile: rows n0..n0+127, cols k0..k0+63 (bf16), linear LDS, async
        for (int i = 0; i < 4; ++i) {
            int boff = (wid * 4 + i) * 1024 + l * 16;  // byte offset in tile
            int r = boff >> 7;
            int kb = boff & 127;
            const char* src = (const char*)Wihb + (size_t)(n0 + r) * 1024 + (size_t)k0 * 2 + kb;
            __builtin_amdgcn_global_load_lds(
                (const __attribute__((address_space(1))) u32*)src,
                (__attribute__((address_space(3))) u32*)((char*)lB + (wid * 4 + i) * 1024),
                16, 0, 0);
        }
        // A tile: 128 rows (= 2 s x 64 b) x 64 k, fp32->bf16 reg-staged
        for (int i = 0; i < 4; ++i) {
            int c = i * 256 + tid;      // chunk id [0,1024)
            int r = c >> 3;             // tile row = sl*64 + b
            int ck = c & 7;
            int b = r & 63;
            int sl = r >> 6;
            const float* src = inp + ((size_t)(b * 512 + s0 + sl) * 512 + k0 + ck * 8);
            f32x4 x0 = *(const f32x4*)src;
            f32x4 x1 = *(const f32x4*)(src + 4);
            u16x8 o;
            for (int j = 0; j < 4; ++j) { o[j] = f2bf(x0[j]); o[4 + j] = f2bf(x1[j]); }
            *(u16x8*)(&lA[r * 64 + ck * 8]) = o;
        }
        __syncthreads();
        for (int kk = 0; kk < 2; ++kk) {
            s16x8 af[4], bf[4];
            for (int am = 0; am < 4; ++am)
                af[am] = *(const s16x8*)(&lA[((wid >> 1) * 64 + am * 16 + (l & 15)) * 64 + kk * 32 + (l >> 4) * 8]);
            for (int bn = 0; bn < 4; ++bn)
                bf[bn] = *(const s16x8*)(&lB[((wid & 1) * 64 + bn * 16 + (l & 15)) * 64 + kk * 32 + (l >> 4) * 8]);
            for (int am = 0; am < 4; ++am)
                for (int bn = 0; bn < 4; ++bn)
                    acc[am][bn] = __builtin_amdgcn_mfma_f32_16x16x32_bf16(af[am], bf[bn], acc[am][bn], 0, 0, 0);
        }
    }
    // epilogue: bias + write in phase-2 fragment order
    for (int am = 0; am < 4; ++am) {
        for (int bn = 0; bn < 4; ++bn) {
            int m_base = mtile * 128 + (wid >> 1) * 64 + am * 16;
            int row0 = m_base + ((l >> 4) << 2);   // j = 0 row
            int s = row0 >> 6;
            int b0 = row0 & 63;
            int n = n0 + (wid & 1) * 64 + bn * 16 + (l & 15);
            int g = n >> 9;
            int col = n & 511;
            int ww = col >> 4;
            int mt2 = b0 >> 4;
            size_t el = ((((size_t)s * 32 + ww) * 4 + mt2) * 3 + g) * 256 + l * 4;
            float bias = bih[n];
            u16x4 o;
            for (int j = 0; j < 4; ++j) o[j] = f2bf(acc[am][bn][j] + bias);
            *(u16x4*)(xp + el) = o;
        }
    }
}

// ---------------------------------------------------------------------------
// gru_scan: persistent kernel, 32 WGs x 256 threads (4 waves).
// WG w owns h columns [w*16, w*16+16) => gh rows {g*512 + w*16 + r}.
// W_hh slice lives fragment-ordered in LDS (48 KiB). Wave mt owns batches
// [mt*16, mt*16+16). Each step: agent-scope bf16 loads of full h (bypasses
// stale per-XCD L2), 16x16x32 MFMAs (3 gates x 16 ksteps), fp32 gate math
// with running h in registers, agent-scope h-slice store, outputs, then a
// counter-per-step spin barrier. h double-buffered so one barrier/step works.
// ---------------------------------------------------------------------------
__global__ __launch_bounds__(256) void gru_scan(const u16* __restrict__ xp,
                                                const u16* __restrict__ Wfrag,
                                                const float* __restrict__ bhh,
                                                const float* __restrict__ inp,
                                                float* __restrict__ dout,
                                                u16* __restrict__ hbuf,
                                                int* __restrict__ cnt) {
    const int w = blockIdx.x;      // 0..31
    const int tid = threadIdx.x;
    const int l = tid & 63;
    const int mt = tid >> 6;       // wave id = batch tile
    float* out_res = dout;
    float* out_hid = dout + (size_t)64 * 512 * 512;

    __shared__ u16 wlds[3 * 16 * 64 * 8];  // 48 KiB
    const char* wsrc = (const char*)(Wfrag + (size_t)w * 24576);
    for (int i = 0; i < 12; ++i) {
        int doff = (mt * 12 + i) * 1024;
        __builtin_amdgcn_global_load_lds(
            (const __attribute__((address_space(1))) u32*)(wsrc + doff + l * 16),
            (__attribute__((address_space(3))) u32*)((char*)wlds + doff),
            16, 0, 0);
    }
    const float bh0 = bhh[0 * 512 + w * 16 + (l & 15)];
    const float bh1 = bhh[1 * 512 + w * 16 + (l & 15)];
    const float bh2 = bhh[2 * 512 + w * 16 + (l & 15)];
    float hold[4] = {0.f, 0.f, 0.f, 0.f};
    const int bb = mt * 16 + ((l >> 4) << 2);   // first batch row of this lane
    const int c = w * 16 + (l & 15);            // h column of this lane
    __syncthreads();  // drains global_load_lds (vmcnt) + barrier

    for (int t = 0; t < 512; ++t) {
        // prefetch x_proj fragment + input for residual (independent of h)
        const u16* xpp = xp + ((((size_t)t * 32 + w) * 4 + mt) * 3) * 256 + l * 4;
        u16x4 xv0 = *(const u16x4*)(xpp);
        u16x4 xv1 = *(const u16x4*)(xpp + 256);
        u16x4 xv2 = *(const u16x4*)(xpp + 512);
        float inv[4];
        for (int j = 0; j < 4; ++j)
            inv[j] = inp[((size_t)(bb + j) * 512 + t) * 512 + c];

        if (t > 0) {
            __syncthreads();  // drains all threads' h stores (vmcnt(0) before s_barrier)
            if (tid == 0) {
                __hip_atomic_fetch_add(&cnt[t - 1], 1, __ATOMIC_RELAXED, __HIP_MEMORY_SCOPE_AGENT);
                while (__hip_atomic_load(&cnt[t - 1], __ATOMIC_RELAXED, __HIP_MEMORY_SCOPE_AGENT) < 32) {}
            }
            __syncthreads();
        }

        const u16* hr = hbuf + (size_t)(t & 1) * 32768;
        u16* hw = hbuf + (size_t)((t + 1) & 1) * 32768;

        // A fragments: h rows mt*16+(l&15), k = kk*32 + (l>>4)*8 .. +7
        const u64* hbase = (const u64*)(hr + (size_t)(mt * 16 + (l & 15)) * 512 + ((l >> 4) << 3));
        s16x8 af[16];
        for (int kk = 0; kk < 16; ++kk) {
            u64 lo = __hip_atomic_load(hbase + kk * 8, __ATOMIC_RELAXED, __HIP_MEMORY_SCOPE_AGENT);
            u64 hi = __hip_atomic_load(hbase + kk * 8 + 1, __ATOMIC_RELAXED, __HIP_MEMORY_SCOPE_AGENT);
            union { u64 q[2]; s16x8 v; } u;
            u.q[0] = lo; u.q[1] = hi;
            af[kk] = u.v;
        }

        f32x4 acc0 = (f32x4){0.f, 0.f, 0.f, 0.f};
        f32x4 acc1 = (f32x4){0.f, 0.f, 0.f, 0.f};
        f32x4 acc2 = (f32x4){0.f, 0.f, 0.f, 0.f};
        for (int kk = 0; kk < 16; ++kk) {
            s16x8 b0 = *(const s16x8*)(&wlds[(0 * 16 + kk) * 512 + l * 8]);
            s16x8 b1 = *(const s16x8*)(&wlds[(1 * 16 + kk) * 512 + l * 8]);
            s16x8 b2 = *(const s16x8*)(&wlds[(2 * 16 + kk) * 512 + l * 8]);
            acc0 = __builtin_amdgcn_mfma_f32_16x16x32_bf16(af[kk], b0, acc0, 0, 0, 0);
            acc1 = __builtin_amdgcn_mfma_f32_16x16x32_bf16(af[kk], b1, acc1, 0, 0, 0);
            acc2 = __builtin_amdgcn_mfma_f32_16x16x32_bf16(af[kk], b2, acc2, 0, 0, 0);
        }

        float hn[4];
        for (int j = 0; j < 4; ++j) {
            float xr = bf2f(xv0[j]), xz = bf2f(xv1[j]), xn = bf2f(xv2[j]);
            float rr = 1.f / (1.f + __expf(-(xr + acc0[j] + bh0)));
            float zz = 1.f / (1.f + __expf(-(xz + acc1[j] + bh1)));
            float nx = xn + rr * (acc2[j] + bh2);
            float e2 = __expf(-2.f * nx);
            float nn = (1.f - e2) / (1.f + e2);
            float h = (1.f - zz) * nn + zz * hold[j];
            hold[j] = h;
            hn[j] = h;
        }
        for (int j = 0; j < 4; ++j) {
            __hip_atomic_store(hw + (size_t)(bb + j) * 512 + c, f2bf(hn[j]),
                               __ATOMIC_RELAXED, __HIP_MEMORY_SCOPE_AGENT);
            size_t oi = ((size_t)(bb + j) * 512 + t) * 512 + c;
            out_hid[oi] = hn[j];
            out_res[oi] = inv[j] + hn[j];
        }
    }
}

// ---------------------------------------------------------------------------
// Workspace layout (bytes):
//   [0, 4096)          barrier counters (512 ints used)   -- memset 0
//   [4096, 69632)      h double buffer 0 (bf16 64x512)    -- memset 0 (= h_{-1})
//   [69632, 135168)    h double buffer 1
//   [135168, 1708032)  Wfrag bf16 (1.5 MiB)
//   [1708032, 3280896) W_ih bf16 (1.5 MiB)
//   [3280896, ~103.9M) x_proj bf16, fragment-ordered (96 MiB)
// ---------------------------------------------------------------------------
extern "C" void kernel_launch(void* const* d_in, const int* in_sizes, int n_in,
                              void* d_out, int out_size, void* d_ws, size_t ws_size,
                              hipStream_t stream) {
    const float* inp = (const float*)d_in[0];
    const float* Wih = (const float*)d_in[1];
    const float* Whh = (const float*)d_in[2];
    const float* bih = (const float*)d_in[3];
    const float* bhh = (const float*)d_in[4];
    float* out = (float*)d_out;

    char* ws = (char*)d_ws;
    int* cnt   = (int*)ws;
    u16* hbuf  = (u16*)(ws + 4096);
    u16* Wfrag = (u16*)(ws + 135168);
    u16* Wihb  = (u16*)(ws + 1708032);
    u16* xp    = (u16*)(ws + 3280896);

    hipMemsetAsync(ws, 0, 4096 + 65536, stream);  // counters + h_{-1} = 0
    hipLaunchKernelGGL(prep, dim3(384), dim3(256), 0, stream, Wih, Whh, Wihb, Wfrag);
    hipLaunchKernelGGL(gemm_xproj, dim3(3072), dim3(256), 0, stream, inp, Wihb, bih, xp);
    hipLaunchKernelGGL(gru_scan, dim3(32), dim3(256), 0, stream, xp, Wfrag, bhh, inp, out, hbuf, cnt);
}